// Round 10
// baseline (475.088 us; speedup 1.0000x reference)
//
#include <hip/hip_runtime.h>

typedef unsigned short u16;
typedef unsigned int   u32;

#define NN   2060          // graph nodes
#define FF   901           // feature dim
#define HP   904           // padded row stride for h (bf16) / g (f32)
#define MM   1778          // fused rows
#define EE   131840        // edges (w/o self loops)
#define ETOT 133900        // edges + self loops
#define NTR  100000
#define NOUT 130000
#define MP   2112          // padded M (33*64)
#define KP   2080          // padded K (65*32)
#define NP   960           // padded N (15*64)
#define EPSV 1e-5f
#define NTOT 1601978.0     // MM*FF
#define GRD  512           // persistent grid (2 blocks/CU x 256 CUs)

typedef __attribute__((ext_vector_type(4))) float f32x4;
typedef __attribute__((ext_vector_type(8))) short bf16x8;

#define GLL16(g,l) __builtin_amdgcn_global_load_lds( \
    (const __attribute__((address_space(1))) u32*)(g), \
    (__attribute__((address_space(3))) u32*)(l), 16, 0, 0)

__device__ __forceinline__ float bf2f(u16 u){ return __uint_as_float(((u32)u)<<16); }
__device__ __forceinline__ u16 f2bf(float f){
  u32 b = __float_as_uint(f);
  return (u16)((b + 0x7fffu + ((b>>16)&1u)) >> 16);
}
__device__ __forceinline__ float ldf(const void* p, size_t i, int bf){
  return bf ? bf2f(((const u16*)p)[i]) : ((const float*)p)[i];
}
__device__ __forceinline__ u16 ldb(const void* p, size_t i, int bf){
  return bf ? ((const u16*)p)[i] : f2bf(((const float*)p)[i]);
}
__device__ __forceinline__ float waveSum(float v){
  #pragma unroll
  for (int o = 32; o; o >>= 1) v += __shfl_down(v, o);
  return v;
}
__device__ __forceinline__ int waveSumI(int v){
  #pragma unroll
  for (int o = 32; o; o >>= 1) v += __shfl_down(v, o);
  return v;
}
__device__ __forceinline__ int flagWave(const u32* __restrict__ x){
  int l = threadIdx.x & 63;
  u32 w0 = x[l], w1 = x[l + 64];
  int big = (((w0 >> 7)  & 0xFFu) >= 0xC0u) + (((w0 >> 23) & 0xFFu) >= 0xC0u)
          + (((w1 >> 7)  & 0xFFu) >= 0xC0u) + (((w1 >> 23) & 0xFFu) >= 0xC0u);
  big = waveSumI(big);
  return (__shfl(big, 0) >= 8) ? 0 : 1;
}
__device__ __forceinline__ void edgeSD(const int* __restrict__ ei, int e, int& src, int& dst){
  if (e < EE){ src = ei[e]; dst = ei[EE + e]; } else { src = dst = e - EE; }
}

// ---- grid barrier: ONE RMW per block (arrival); waiters poll with agent-scope
// atomic LOADS (no RMW storm — round-9 postmortem: RMW polling cost ~40 µs/barrier).
__device__ __forceinline__ void gbar(int* cnt, int* gen){
  __syncthreads();
  if (threadIdx.x == 0){
    __threadfence();                        // release this block's writes
    int g = __hip_atomic_load(gen, __ATOMIC_RELAXED, __HIP_MEMORY_SCOPE_AGENT);
    if (__hip_atomic_fetch_add(cnt, 1, __ATOMIC_ACQ_REL, __HIP_MEMORY_SCOPE_AGENT) == GRD - 1){
      __hip_atomic_store(cnt, 0, __ATOMIC_RELAXED, __HIP_MEMORY_SCOPE_AGENT);
      __hip_atomic_store(gen, g + 1, __ATOMIC_RELEASE, __HIP_MEMORY_SCOPE_AGENT);
    } else {
      for (long it = 0; it < (1L << 24); ++it){
        if (__hip_atomic_load(gen, __ATOMIC_ACQUIRE, __HIP_MEMORY_SCOPE_AGENT) != g) break;
        __builtin_amdgcn_s_sleep(16);
      }
    }
    __threadfence();                        // acquire side
  }
  __syncthreads();
}

// ---------- fused prep: A-pad(vec8) | Wg transpose | coll1 | edge counting ----------
__global__ __launch_bounds__(256) void pad_k(const void* __restrict__ X, const void* __restrict__ Wg,
                                             const void* __restrict__ W3, const void* __restrict__ W4,
                                             const void* __restrict__ b3, const void* __restrict__ b4,
                                             const int* __restrict__ ei,
                                             u16* __restrict__ Ap, u16* __restrict__ BT,
                                             float* __restrict__ u3, float* __restrict__ cp,
                                             int* __restrict__ cnts, int* bfp){
  __shared__ u16 tt[32][33];
  int bf = flagWave((const u32*)X);
  int blk = blockIdx.x, tid = threadIdx.x;
  if (blk == 0 && tid == 0) *bfp = bf;
  if (blk < MP){
    int row = blk;
    for (int c0 = tid * 8; c0 < KP; c0 += 2048){
      u16 v[8] = {0,0,0,0,0,0,0,0};
      if (row < NN){
        if (c0 + 8 <= NN){
          if (bf){
            ushort4 t0 = *(const ushort4*)((const u16*)X + (size_t)row * NN + c0);
            ushort4 t1 = *(const ushort4*)((const u16*)X + (size_t)row * NN + c0 + 4);
            v[0]=t0.x; v[1]=t0.y; v[2]=t0.z; v[3]=t0.w;
            v[4]=t1.x; v[5]=t1.y; v[6]=t1.z; v[7]=t1.w;
          } else {
            float4 t0 = *(const float4*)((const float*)X + (size_t)row * NN + c0);
            float4 t1 = *(const float4*)((const float*)X + (size_t)row * NN + c0 + 4);
            v[0]=f2bf(t0.x); v[1]=f2bf(t0.y); v[2]=f2bf(t0.z); v[3]=f2bf(t0.w);
            v[4]=f2bf(t1.x); v[5]=f2bf(t1.y); v[6]=f2bf(t1.z); v[7]=f2bf(t1.w);
          }
        } else {
          #pragma unroll
          for (int i = 0; i < 8; ++i)
            if (c0 + i < NN) v[i] = ldb(X, (size_t)row * NN + c0 + i, bf);
        }
      }
      *(uint4*)(Ap + (size_t)row * KP + c0) = *(const uint4*)v;
    }
  } else if (blk < MP + 1950){
    int t = blk - MP;
    int kb = (t % 65) * 32, nb = (t / 65) * 32;
    int tx = tid & 31, ty = tid >> 5;
    #pragma unroll
    for (int i = 0; i < 4; ++i){
      int k = kb + ty + 8*i, n = nb + tx;
      u16 v = 0;
      if (k < NN && n < FF) v = ldb(Wg, (size_t)k * FF + n, bf);
      tt[ty + 8*i][tx] = v;
    }
    __syncthreads();
    #pragma unroll
    for (int i = 0; i < 4; ++i){
      int n = nb + ty + 8*i, k = kb + tx;
      if (n < NP && k < KP) BT[(size_t)n * KP + k] = tt[tx][ty + 8*i];
    }
  } else if (blk < MP + 1950 + 514){
    if (tid >= 64) return;
    int ob = blk - (MP + 1950);
    if (ob > 512) return;
    float s = (ob < 512) ? ldf(W3, (size_t)ob*64 + tid, bf) * ldf(W4, tid, bf)
                         : ldf(b3, tid, bf) * ldf(W4, tid, bf);
    s = waveSum(s);
    if (tid == 0){ if (ob < 512) u3[ob] = s; else cp[0] = s + ldf(b4, 0, bf); }
  } else {
    int e = (blk - (MP + 1950 + 514)) * 256 + tid;
    if (e >= ETOT) return;
    int src, dst; edgeSD(ei, e, src, dst);
    atomicAdd(&cnts[dst], 1);
  }
}

// ---------- scan (block 0) + coll2 ----------
__global__ __launch_bounds__(256) void scan_k(const int* __restrict__ counts, int* __restrict__ offs,
                                              const void* __restrict__ W2, const void* __restrict__ b2,
                                              const float* __restrict__ u3, float* __restrict__ u2,
                                              float* __restrict__ cp, const int* bfp){
  int blk = blockIdx.x, tid = threadIdx.x;
  if (blk == 0){
    __shared__ int part[256];
    const int CH = (NN + 255) / 256;
    int base = tid * CH, s = 0;
    for (int i = 0; i < CH; ++i){ int idx = base + i; if (idx < NN) s += counts[idx]; }
    part[tid] = s;
    __syncthreads();
    if (tid == 0){ int run = 0; for (int i = 0; i < 256; ++i){ int v = part[i]; part[i] = run; run += v; } }
    __syncthreads();
    int run = part[tid];
    for (int i = 0; i < CH; ++i){ int idx = base + i; if (idx < NN){ offs[idx] = run; run += counts[idx]; } }
    if (tid == 255) offs[NN] = run;
  } else {
    int bf = *bfp;
    __shared__ float sh[4];
    #pragma unroll 1
    for (int r = 0; r < 2; ++r){
      int ob = (blk - 1) * 2 + r;
      if (ob <= 1024){
        float s = 0;
        if (ob < 1024){ for (int j = tid; j < 512; j += 256) s += ldf(W2, (size_t)ob*512 + j, bf) * u3[j]; }
        else          { for (int j = tid; j < 512; j += 256) s += ldf(b2, j, bf) * u3[j]; }
        s = waveSum(s);
        __syncthreads();
        if ((tid & 63) == 0) sh[tid >> 6] = s;
        __syncthreads();
        if (tid == 0){ float t = sh[0]+sh[1]+sh[2]+sh[3]; if (ob < 1024) u2[ob] = t; else cp[1] = t; }
      }
    }
  }
}

// ---------- GEMM (double-buffered) + coll3 ----------
__global__ __launch_bounds__(256) void gemm_k(const u16* __restrict__ A, const u16* __restrict__ BT,
                                              u16* __restrict__ h,
                                              const void* __restrict__ W1, const void* __restrict__ b1,
                                              const float* __restrict__ u2, float* __restrict__ u1,
                                              float* __restrict__ cp, const int* bfp){
  __shared__ __align__(16) u16 sA[2][64*32];
  __shared__ __align__(16) u16 sB[2][64*32];
  __shared__ float shr[4];
  int blk = blockIdx.x, tid = threadIdx.x;
  if (blk >= 495){
    int bf = *bfp;
    #pragma unroll 1
    for (int r = 0; r < 4; ++r){
      int ob = (blk - 495) * 4 + r;
      if (ob <= 1802){
        float s = 0;
        if (ob < 1802){ for (int j = tid; j < 1024; j += 256) s += ldf(W1, (size_t)ob*1024 + j, bf) * u2[j]; }
        else          { for (int j = tid; j < 1024; j += 256) s += ldf(b1, j, bf) * u2[j]; }
        s = waveSum(s);
        __syncthreads();
        if ((tid & 63) == 0) shr[tid >> 6] = s;
        __syncthreads();
        if (tid == 0){ float t = shr[0]+shr[1]+shr[2]+shr[3]; if (ob < 1802) u1[ob] = t; else cp[2] = t; }
      }
    }
    return;
  }
  int bm = (blk % 33) * 64, bn = (blk / 33) * 64;
  int lane = tid & 63, wave = tid >> 6;
  int wm = (wave >> 1) * 32, wn = (wave & 1) * 32;
  f32x4 acc[2][2] = {};
  int srow = tid >> 2;
  int schunk = (tid & 3) ^ ((tid >> 3) & 3);
  const u16* gA = A  + (size_t)(bm + srow) * KP + schunk * 8;
  const u16* gB = BT + (size_t)(bn + srow) * KP + schunk * 8;
  int fr = lane & 15, quad = lane >> 4;
  int qs = quad ^ ((fr >> 1) & 3);
  const int KIT = KP / 32;
  GLL16(gA, &sA[0][wave * 512]);
  GLL16(gB, &sB[0][wave * 512]);
  for (int kt = 0; kt < KIT; ++kt){
    int cur = kt & 1;
    __syncthreads();
    if (kt + 1 < KIT){
      GLL16(gA + (kt + 1) * 32, &sA[cur ^ 1][wave * 512]);
      GLL16(gB + (kt + 1) * 32, &sB[cur ^ 1][wave * 512]);
    }
    bf16x8 a0 = *(const bf16x8*)&sA[cur][(wm      + fr) * 32 + qs * 8];
    bf16x8 a1 = *(const bf16x8*)&sA[cur][(wm + 16 + fr) * 32 + qs * 8];
    bf16x8 b0 = *(const bf16x8*)&sB[cur][(wn      + fr) * 32 + qs * 8];
    bf16x8 b1 = *(const bf16x8*)&sB[cur][(wn + 16 + fr) * 32 + qs * 8];
    acc[0][0] = __builtin_amdgcn_mfma_f32_16x16x32_bf16(a0, b0, acc[0][0], 0,0,0);
    acc[0][1] = __builtin_amdgcn_mfma_f32_16x16x32_bf16(a0, b1, acc[0][1], 0,0,0);
    acc[1][0] = __builtin_amdgcn_mfma_f32_16x16x32_bf16(a1, b0, acc[1][0], 0,0,0);
    acc[1][1] = __builtin_amdgcn_mfma_f32_16x16x32_bf16(a1, b1, acc[1][1], 0,0,0);
  }
  #pragma unroll
  for (int im = 0; im < 2; ++im)
    #pragma unroll
    for (int in = 0; in < 2; ++in)
      #pragma unroll
      for (int i = 0; i < 4; ++i){
        int row = bm + wm + im*16 + quad*4 + i;
        int col = bn + wn + in*16 + fr;
        if (row < NN && col < FF) h[(size_t)row * HP + col] = f2bf(acc[im][in][i]);
      }
}

// ---------- persistent mid: asd -> barrier -> edge softmax/CSR ----------
__global__ __launch_bounds__(256, 2) void mid_k(const u16* __restrict__ h, const void* att_s, const void* att_d,
                                                const int* __restrict__ ei,
                                                float* __restrict__ a_s, float* __restrict__ a_d,
                                                float* __restrict__ denom, const int* __restrict__ offs,
                                                int* __restrict__ fill, int* __restrict__ csrS,
                                                float* __restrict__ csrW, const int* bfp, int* bar){
  int blk = blockIdx.x, tid = threadIdx.x, bf = *bfp;
  {
    int wv = tid >> 6, lane = tid & 63;
    for (int n = blk * 4 + wv; n < NN; n += GRD * 4){
      float ss = 0, sd = 0;
      for (int f = lane; f < FF; f += 64){
        float hv = bf2f(h[(size_t)n * HP + f]);
        ss += hv * ldf(att_s, f, bf);
        sd += hv * ldf(att_d, f, bf);
      }
      ss = waveSum(ss); sd = waveSum(sd);
      if (lane == 0){ a_s[n] = ss; a_d[n] = sd; }
    }
  }
  gbar(&bar[0], &bar[1]);
  for (int e = blk * 256 + tid; e < ETOT; e += GRD * 256){
    int src, dst; edgeSD(ei, e, src, dst);
    float x = a_s[src] + a_d[dst];
    float ev = x > 0.f ? x : 0.2f * x;
    float ex = expf(ev);
    atomicAdd(&denom[dst], ex);
    int pos = offs[dst] + atomicAdd(&fill[dst], 1);
    csrS[pos] = src; csrW[pos] = ex;
  }
}

// ---------- aggregation (+ statsA fused) ----------
__device__ __forceinline__ void acc8(float* a, uint4 v, float w){
  u32 arr[4] = {v.x, v.y, v.z, v.w};
  #pragma unroll
  for (int i = 0; i < 4; ++i){
    a[2*i]   += w * __uint_as_float((arr[i] & 0xFFFFu) << 16);
    a[2*i+1] += w * __uint_as_float(arr[i] & 0xFFFF0000u);
  }
}
__global__ __launch_bounds__(128) void aggr_k(const u16* __restrict__ h, const int* __restrict__ offs,
                                              const int* __restrict__ csr_src, const float* __restrict__ csr_w,
                                              const float* __restrict__ denom, const void* gat_b,
                                              const void* __restrict__ mirna,
                                              const void* lw1, const void* lb1,
                                              float* __restrict__ g, float* __restrict__ gp,
                                              float2* __restrict__ pA, const int* bfp){
  int bf = *bfp;
  int m = blockIdx.x, tid = threadIdx.x;
  int dst = m < 901 ? m : m + 282;
  int o0 = offs[dst], o1 = offs[dst + 1];
  float inv = 1.0f / denom[dst];
  __shared__ int   sS[128];
  __shared__ float sW[128];
  __shared__ float red[4][2];
  const int c = tid;
  float a[8] = {0,0,0,0,0,0,0,0};
  for (int base = o0; base < o1; base += 128){
    int nb = min(128, o1 - base);
    __syncthreads();
    if (tid < nb){ sS[tid] = csr_src[base + tid]; sW[tid] = csr_w[base + tid] * inv; }
    __syncthreads();
    if (c < 113){
      int k = 0;
      for (; k + 4 <= nb; k += 4){
        int   i0 = sS[k], i1 = sS[k+1], i2 = sS[k+2], i3 = sS[k+3];
        float w0 = sW[k], w1 = sW[k+1], w2 = sW[k+2], w3 = sW[k+3];
        uint4 v0 = ((const uint4*)(h + (size_t)i0 * HP))[c];
        uint4 v1 = ((const uint4*)(h + (size_t)i1 * HP))[c];
        uint4 v2 = ((const uint4*)(h + (size_t)i2 * HP))[c];
        uint4 v3 = ((const uint4*)(h + (size_t)i3 * HP))[c];
        acc8(a, v0, w0); acc8(a, v1, w1); acc8(a, v2, w2); acc8(a, v3, w3);
      }
      for (; k < nb; ++k){
        uint4 v0 = ((const uint4*)(h + (size_t)sS[k] * HP))[c];
        acc8(a, v0, sW[k]);
      }
    }
  }
  float w00 = ldf(lw1,0,bf), w01 = ldf(lw1,1,bf), bb = ldf(lb1,0,bf);
  float sx0 = 0, sx1 = 0, sl = 0, sl2 = 0;
  if (c < 113){
    int f0 = 8 * c;
    float r[8];
    #pragma unroll
    for (int i = 0; i < 8; ++i){
      bool inb = (f0 + i) < FF;
      float v = a[i] + (inb ? ldf(gat_b, f0 + i, bf) : 0.f);
      v = v > 0.f ? v : 0.f;
      r[i] = inb ? v : 0.f;
      if (inb){
        float x1 = ldf(mirna, (size_t)m * FF + f0 + i, bf);
        float xl = w00*r[i] + w01*x1 + bb;
        sx0 += r[i]; sx1 += x1; sl += xl; sl2 += xl*xl;
      }
    }
    float4* go = (float4*)(g + (size_t)dst * HP);
    go[2*c]   = make_float4(r[0], r[1], r[2], r[3]);
    go[2*c+1] = make_float4(r[4], r[5], r[6], r[7]);
  }
  sx0 = waveSum(sx0); sx1 = waveSum(sx1); sl = waveSum(sl); sl2 = waveSum(sl2);
  int wv = tid >> 6;
  if ((tid & 63) == 0){ red[0][wv]=sx0; red[1][wv]=sx1; red[2][wv]=sl; red[3][wv]=sl2; }
  __syncthreads();
  if (tid == 0){
    gp[2*m]   = (red[0][0]+red[0][1]) / (float)FF;
    gp[2*m+1] = (red[1][0]+red[1][1]) / (float)FF;
    pA[m] = make_float2(red[2][0]+red[2][1], red[3][0]+red[3][1]);
  }
}

// ---------- persistent tail: [pA-reduce local] xg/statsB | [pB-reduce local] fs | out ----------
__global__ __launch_bounds__(256, 2) void tail_k(
    const float* __restrict__ g, const void* __restrict__ mirna,
    const void* lw1, const void* lb1, const void* lw2,
    const void* gw1, const void* gb1, const void* gw2,
    const float* __restrict__ u1, const int* __restrict__ tr, const int* __restrict__ te,
    const float* __restrict__ cp, const float* __restrict__ gp,
    const float2* __restrict__ pA, float2* __restrict__ pB,
    float* __restrict__ xg2b, float* __restrict__ s0, float* __restrict__ s1,
    void* __restrict__ out, const int* bfp, int* bar)
{
  __shared__ float xr[4][FF];
  __shared__ float yr[4][FF];
  __shared__ float xs[MM];              // block 0 only (xg scratch)
  __shared__ float sred[2][4];
  __shared__ float bc[2];
  int blk = blockIdx.x, tid = threadIdx.x, bf = *bfp;
  int wv = tid >> 6;
  float w00 = ldf(lw1,0,bf), w01 = ldf(lw1,1,bf), bb = ldf(lb1,0,bf);

  // ---- local pA reduction (every block; no barrier needed — pA from prior kernel) ----
  float mu1, rs1;
  {
    float s = 0, s2 = 0;
    for (int m = tid; m < MM; m += 256){ float2 p = pA[m]; s += p.x; s2 += p.y; }
    s = waveSum(s); s2 = waveSum(s2);
    if ((tid & 63) == 0){ sred[0][wv] = s; sred[1][wv] = s2; }
    __syncthreads();
    if (tid == 0){
      float t  = sred[0][0]+sred[0][1]+sred[0][2]+sred[0][3];
      float t2 = sred[1][0]+sred[1][1]+sred[1][2]+sred[1][3];
      float mu = (float)((double)t / NTOT);
      bc[0] = mu;
      bc[1] = rsqrtf((float)((double)t2 / NTOT) - mu*mu + EPSV);
    }
    __syncthreads();
    mu1 = bc[0]; rs1 = bc[1];
    __syncthreads();
  }

  // ---- phase 0: block 0 computes xg2b; all blocks cache rows + statsB partials ----
  if (blk == 0){
    float g10 = ldf(gw1,0,bf), g11 = ldf(gw1,1,bf), b1v = ldf(gb1,0,bf);
    float s = 0, s2 = 0;
    for (int m = tid; m < MM; m += 256){
      float v = g10*gp[2*m] + g11*gp[2*m+1] + b1v;
      xs[m] = v; s += v; s2 += v*v;
    }
    s = waveSum(s); s2 = waveSum(s2);
    if ((tid & 63) == 0){ sred[0][wv] = s; sred[1][wv] = s2; }
    __syncthreads();
    if (tid == 0){
      float t  = sred[0][0]+sred[0][1]+sred[0][2]+sred[0][3];
      float t2 = sred[1][0]+sred[1][1]+sred[1][2]+sred[1][3];
      float mean = t / (float)MM, var = t2 / (float)MM - mean*mean;
      bc[0] = mean; bc[1] = rsqrtf(var + EPSV);
    }
    __syncthreads();
    float mean = bc[0], rs = bc[1];
    s = 0; s2 = 0;
    for (int m = tid; m < MM; m += 256){
      float r = (xs[m] - mean) * rs; r = r > 0.f ? r : 0.f;
      xs[m] = r; s += r; s2 += r*r;
    }
    s = waveSum(s); s2 = waveSum(s2);
    __syncthreads();
    if ((tid & 63) == 0){ sred[0][wv] = s; sred[1][wv] = s2; }
    __syncthreads();
    if (tid == 0){
      float t  = sred[0][0]+sred[0][1]+sred[0][2]+sred[0][3];
      float t2 = sred[1][0]+sred[1][1]+sred[1][2]+sred[1][3];
      float mrg = t / (float)MM, vrg = t2 / (float)MM - mrg*mrg;
      float g20 = ldf(gw2,0,bf), g21 = ldf(gw2,1,bf);
      bc[0] = mrg;
      sred[0][0] = g20 * rsqrtf(g20*g20*vrg + EPSV);
      sred[0][1] = g21 * rsqrtf(g21*g21*vrg + EPSV);
    }
    __syncthreads();
    float mrg = bc[0], c0 = sred[0][0], c1 = sred[0][1];
    for (int m = tid; m < MM; m += 256){
      float d = xs[m] - mrg;
      xg2b[2*m] = c0 * d; xg2b[2*m+1] = c1 * d;
    }
    __syncthreads();
  }
  #pragma unroll 1
  for (int r = 0; r < 4; ++r){
    int m = blk + GRD * r;
    if (m >= MM) break;
    int gr = m < 901 ? m : m + 282;
    for (int w = tid; w < FF; w += 256){
      xr[r][w] = g[(size_t)gr * HP + w];
      yr[r][w] = ldf(mirna, (size_t)m * FF + w, bf);
    }
    __syncthreads();
    float sr = 0, sr2 = 0;
    for (int w = tid; w < FF; w += 256){
      float xl = w00*xr[r][w] + w01*yr[r][w] + bb;
      float rr = (xl - mu1) * rs1; rr = rr > 0.f ? rr : 0.f;
      sr += rr; sr2 += rr*rr;
    }
    sr = waveSum(sr); sr2 = waveSum(sr2);
    __syncthreads();
    if ((tid & 63) == 0){ sred[0][wv] = sr; sred[1][wv] = sr2; }
    __syncthreads();
    if (tid == 0) pB[m] = make_float2(sred[0][0]+sred[0][1]+sred[0][2]+sred[0][3],
                                      sred[1][0]+sred[1][1]+sred[1][2]+sred[1][3]);
  }
  gbar(&bar[0], &bar[1]);

  // ---- phase 1: local pB reduction (every block) + fs per cached row ----
  {
    float s = 0, s2 = 0;
    for (int m = tid; m < MM; m += 256){ float2 p = pB[m]; s += p.x; s2 += p.y; }
    s = waveSum(s); s2 = waveSum(s2);
    __syncthreads();
    if ((tid & 63) == 0){ sred[0][wv] = s; sred[1][wv] = s2; }
    __syncthreads();
    if (tid == 0){
      float t  = sred[0][0]+sred[0][1]+sred[0][2]+sred[0][3];
      float t2 = sred[1][0]+sred[1][1]+sred[1][2]+sred[1][3];
      float mr = (float)((double)t / NTOT);
      float vr = (float)((double)t2 / NTOT) - mr*mr;
      float l20 = ldf(lw2,0,bf), l21 = ldf(lw2,1,bf);
      bc[0] = mr;
      sred[0][0] = l20 * rsqrtf(l20*l20*vr + EPSV);
      sred[0][1] = l21 * rsqrtf(l21*l21*vr + EPSV);
    }
    __syncthreads();
    float mr = bc[0], A0 = sred[0][0], A1 = sred[0][1];
    __syncthreads();
    #pragma unroll 1
    for (int r = 0; r < 4; ++r){
      int m = blk + GRD * r;
      if (m >= MM) break;
      float xa = xg2b[2*m], xb = xg2b[2*m+1];
      float p0 = 0, p1 = 0;
      for (int w = tid; w < FF; w += 256){
        float x0 = xr[r][w], x1 = yr[r][w];
        float xl = w00*x0 + w01*x1 + bb;
        float rr = (xl - mu1) * rs1; rr = rr > 0.f ? rr : 0.f;
        float rc = rr - mr;
        float z0 = A0*rc + xa, z1 = A1*rc + xb;
        float sg0 = 1.f / (1.f + expf(-z0));
        float sg1 = 1.f / (1.f + expf(-z1));
        float f = 0.5f * (x0*sg0 + x1*sg1);
        p0 += f * u1[w]; p1 += f * u1[901 + w];
      }
      p0 = waveSum(p0); p1 = waveSum(p1);
      __syncthreads();
      if ((tid & 63) == 0){ sred[0][wv] = p0; sred[1][wv] = p1; }
      __syncthreads();
      if (tid == 0){
        s0[m] = sred[0][0]+sred[0][1]+sred[0][2]+sred[0][3];
        s1[m] = sred[1][0]+sred[1][1]+sred[1][2]+sred[1][3];
      }
    }
  }
  gbar(&bar[0], &bar[1]);

  // ---- phase 2: final scores ----
  {
    float cc = cp[0] + cp[1] + cp[2];
    for (int b = blk * 256 + tid; b < NOUT; b += GRD * 256){
      int i, j;
      if (b < NTR){ i = tr[2*b]; j = tr[2*b + 1]; }
      else { int t = b - NTR; i = te[2*t]; j = te[2*t + 1]; }
      float z = s0[i] + s1[j] + cc;
      float v = 1.f / (1.f + expf(-z));
      if (bf) ((u16*)out)[b] = f2bf(v);
      else    ((float*)out)[b] = v;
    }
  }
}

extern "C" void kernel_launch(void* const* d_in, const int* in_sizes, int n_in,
                              void* d_out, int out_size, void* d_ws, size_t ws_size,
                              hipStream_t stream){
  const void* x_feat = d_in[0];
  const void* mirna  = d_in[1];
  const void* Wg     = d_in[2];
  const void* att_s  = d_in[3];
  const void* att_d  = d_in[4];
  const void* gat_b  = d_in[5];
  const void* lw1    = d_in[6];
  const void* lb1    = d_in[7];
  const void* lw2    = d_in[8];
  const void* gw1    = d_in[10];
  const void* gb1    = d_in[11];
  const void* gw2    = d_in[12];
  const void* W1     = d_in[14];
  const void* b1     = d_in[15];
  const void* W2     = d_in[16];
  const void* b2     = d_in[17];
  const void* W3     = d_in[18];
  const void* b3     = d_in[19];
  const void* W4     = d_in[20];
  const void* b4     = d_in[21];
  const int* ei      = (const int*)d_in[22];
  const int* tr      = (const int*)d_in[23];
  const int* te      = (const int*)d_in[24];

  char* ws = (char*)d_ws;
  size_t off = 0;
  auto alloc = [&](size_t bytes)->size_t{ size_t o = off; off += (bytes + 255) & ~(size_t)255; return o; };
  size_t oA  = alloc((size_t)MP*KP*2);     // padded A; later overlaid by g [NN][HP] f32
  size_t oBT = alloc((size_t)NP*KP*2);
  size_t oH  = alloc((size_t)NN*HP*2);
  size_t oCS = alloc((size_t)ETOT*4);
  size_t oCW = alloc((size_t)ETOT*4);
  size_t oAS = alloc(NN*4);
  size_t oAD = alloc(NN*4);
  size_t oOF = alloc((NN+1)*4);
  size_t oGP = alloc(MM*2*4);
  size_t oXG = alloc(MM*2*4);
  size_t oS0 = alloc(MM*4);
  size_t oS1 = alloc(MM*4);
  size_t oU3 = alloc(512*4);
  size_t oU2 = alloc(1024*4);
  size_t oU1 = alloc(1802*4);
  size_t oPA = alloc(MM*8);
  size_t oPB = alloc(MM*8);
  size_t oCP = alloc(3*4);
  size_t oBF = alloc(4);
  size_t zstart = off;                     // ---- zeroed region ----
  size_t oCT = alloc(NN*4);                // counts
  size_t oFL = alloc(NN*4);                // fill
  size_t oDN = alloc(NN*4);                // denom
  size_t oBR = alloc(4*4);                 // barriers: mid{cnt,gen}, tail{cnt,gen}
  size_t zend = off;

  u16*   Ap   = (u16*)(ws+oA);
  u16*   BT   = (u16*)(ws+oBT);
  u16*   h    = (u16*)(ws+oH);
  float* gbuf = (float*)(ws+oA);           // overlay: A dead after gemm
  int*   csrS = (int*)(ws+oCS);
  float* csrW = (float*)(ws+oCW);
  float* a_s  = (float*)(ws+oAS);
  float* a_d  = (float*)(ws+oAD);
  int*   offs = (int*)(ws+oOF);
  float* gp   = (float*)(ws+oGP);
  float* xg2b = (float*)(ws+oXG);
  float* s0   = (float*)(ws+oS0);
  float* s1   = (float*)(ws+oS1);
  float* u3   = (float*)(ws+oU3);
  float* u2   = (float*)(ws+oU2);
  float* u1   = (float*)(ws+oU1);
  float2* pA  = (float2*)(ws+oPA);
  float2* pB  = (float2*)(ws+oPB);
  float* cp   = (float*)(ws+oCP);
  int*   bfp  = (int*)(ws+oBF);
  int*   cnts = (int*)(ws+oCT);
  int*   fill = (int*)(ws+oFL);
  float* denom= (float*)(ws+oDN);
  int*   barM = (int*)(ws+oBR);
  int*   barT = (int*)(ws+oBR+8);

  hipMemsetAsync(ws + zstart, 0, zend - zstart, stream);

  pad_k  <<<MP + 1950 + 514 + (ETOT+255)/256, 256, 0, stream>>>(
      x_feat, Wg, W3, W4, b3, b4, ei, Ap, BT, u3, cp, cnts, bfp);
  scan_k <<<514, 256, 0, stream>>>(cnts, offs, W2, b2, u3, u2, cp, bfp);
  gemm_k <<<495 + 451, 256, 0, stream>>>(Ap, BT, h, W1, b1, u2, u1, cp, bfp);
  mid_k  <<<GRD, 256, 0, stream>>>(h, att_s, att_d, ei, a_s, a_d, denom, offs, fill, csrS, csrW, bfp, barM);
  aggr_k <<<MM, 128, 0, stream>>>(h, offs, csrS, csrW, denom, gat_b, mirna, lw1, lb1, gbuf, gp, pA, bfp);
  tail_k <<<GRD, 256, 0, stream>>>(gbuf, mirna, lw1, lb1, lw2, gw1, gb1, gw2, u1, tr, te,
                                   cp, gp, pA, pB, xg2b, s0, s1, d_out, bfp, barT);
}

// Round 11
// 254.757 us; speedup vs baseline: 1.8649x; 1.8649x over previous
//
#include <hip/hip_runtime.h>

typedef unsigned short u16;
typedef unsigned int   u32;

#define NN   2060          // graph nodes
#define FF   901           // feature dim
#define HP   904           // padded row stride for h (bf16) / g (f32)
#define MM   1778          // fused rows
#define EE   131840        // edges (w/o self loops)
#define ETOT 133900        // edges + self loops
#define NTR  100000
#define NOUT 130000
#define MP   2112          // padded M (33*64)
#define KP   2080          // padded K (65*32)
#define NP   960           // padded N (15*64)
#define EPSV 1e-5f
#define NTOT 1601978.0     // MM*FF

typedef __attribute__((ext_vector_type(4))) float f32x4;
typedef __attribute__((ext_vector_type(8))) short bf16x8;

#define GLL16(g,l) __builtin_amdgcn_global_load_lds( \
    (const __attribute__((address_space(1))) u32*)(g), \
    (__attribute__((address_space(3))) u32*)(l), 16, 0, 0)

__device__ __forceinline__ float bf2f(u16 u){ return __uint_as_float(((u32)u)<<16); }
__device__ __forceinline__ u16 f2bf(float f){
  u32 b = __float_as_uint(f);
  return (u16)((b + 0x7fffu + ((b>>16)&1u)) >> 16);
}
__device__ __forceinline__ float ldf(const void* p, size_t i, int bf){
  return bf ? bf2f(((const u16*)p)[i]) : ((const float*)p)[i];
}
__device__ __forceinline__ u16 ldb(const void* p, size_t i, int bf){
  return bf ? ((const u16*)p)[i] : f2bf(((const float*)p)[i]);
}
__device__ __forceinline__ float waveSum(float v){
  #pragma unroll
  for (int o = 32; o; o >>= 1) v += __shfl_down(v, o);
  return v;
}
__device__ __forceinline__ int waveSumI(int v){
  #pragma unroll
  for (int o = 32; o; o >>= 1) v += __shfl_down(v, o);
  return v;
}
__device__ __forceinline__ int flagWave(const u32* __restrict__ x){
  int l = threadIdx.x & 63;
  u32 w0 = x[l], w1 = x[l + 64];
  int big = (((w0 >> 7)  & 0xFFu) >= 0xC0u) + (((w0 >> 23) & 0xFFu) >= 0xC0u)
          + (((w1 >> 7)  & 0xFFu) >= 0xC0u) + (((w1 >> 23) & 0xFFu) >= 0xC0u);
  big = waveSumI(big);
  return (__shfl(big, 0) >= 8) ? 0 : 1;
}
__device__ __forceinline__ void edgeSD(const int* __restrict__ ei, int e, int& src, int& dst){
  if (e < EE){ src = ei[e]; dst = ei[EE + e]; } else { src = dst = e - EE; }
}

// ---------- fused prep: A-pad(vec8) | Wg transpose | coll1 | edge counting ----------
__global__ __launch_bounds__(256) void pad_k(const void* __restrict__ X, const void* __restrict__ Wg,
                                             const void* __restrict__ W3, const void* __restrict__ W4,
                                             const void* __restrict__ b3, const void* __restrict__ b4,
                                             const int* __restrict__ ei,
                                             u16* __restrict__ Ap, u16* __restrict__ BT,
                                             float* __restrict__ u3, float* __restrict__ cp,
                                             int* __restrict__ cnts, int* bfp){
  __shared__ u16 tt[32][33];
  int bf = flagWave((const u32*)X);
  int blk = blockIdx.x, tid = threadIdx.x;
  if (blk == 0 && tid == 0) *bfp = bf;
  if (blk < MP){
    int row = blk;
    for (int c0 = tid * 8; c0 < KP; c0 += 2048){
      u16 v[8] = {0,0,0,0,0,0,0,0};
      if (row < NN){
        if (c0 + 8 <= NN){
          if (bf){
            ushort4 t0 = *(const ushort4*)((const u16*)X + (size_t)row * NN + c0);
            ushort4 t1 = *(const ushort4*)((const u16*)X + (size_t)row * NN + c0 + 4);
            v[0]=t0.x; v[1]=t0.y; v[2]=t0.z; v[3]=t0.w;
            v[4]=t1.x; v[5]=t1.y; v[6]=t1.z; v[7]=t1.w;
          } else {
            float4 t0 = *(const float4*)((const float*)X + (size_t)row * NN + c0);
            float4 t1 = *(const float4*)((const float*)X + (size_t)row * NN + c0 + 4);
            v[0]=f2bf(t0.x); v[1]=f2bf(t0.y); v[2]=f2bf(t0.z); v[3]=f2bf(t0.w);
            v[4]=f2bf(t1.x); v[5]=f2bf(t1.y); v[6]=f2bf(t1.z); v[7]=f2bf(t1.w);
          }
        } else {
          #pragma unroll
          for (int i = 0; i < 8; ++i)
            if (c0 + i < NN) v[i] = ldb(X, (size_t)row * NN + c0 + i, bf);
        }
      }
      *(uint4*)(Ap + (size_t)row * KP + c0) = *(const uint4*)v;
    }
  } else if (blk < MP + 1950){
    int t = blk - MP;
    int kb = (t % 65) * 32, nb = (t / 65) * 32;
    int tx = tid & 31, ty = tid >> 5;
    #pragma unroll
    for (int i = 0; i < 4; ++i){
      int k = kb + ty + 8*i, n = nb + tx;
      u16 v = 0;
      if (k < NN && n < FF) v = ldb(Wg, (size_t)k * FF + n, bf);
      tt[ty + 8*i][tx] = v;
    }
    __syncthreads();
    #pragma unroll
    for (int i = 0; i < 4; ++i){
      int n = nb + ty + 8*i, k = kb + tx;
      if (n < NP && k < KP) BT[(size_t)n * KP + k] = tt[tx][ty + 8*i];
    }
  } else if (blk < MP + 1950 + 514){
    if (tid >= 64) return;
    int ob = blk - (MP + 1950);
    if (ob > 512) return;
    float s = (ob < 512) ? ldf(W3, (size_t)ob*64 + tid, bf) * ldf(W4, tid, bf)
                         : ldf(b3, tid, bf) * ldf(W4, tid, bf);
    s = waveSum(s);
    if (tid == 0){ if (ob < 512) u3[ob] = s; else cp[0] = s + ldf(b4, 0, bf); }
  } else {
    int e = (blk - (MP + 1950 + 514)) * 256 + tid;
    if (e >= ETOT) return;
    int src, dst; edgeSD(ei, e, src, dst);
    atomicAdd(&cnts[dst], 1);
  }
}

// ---------- scan (block 0) + coll2 ----------
__global__ __launch_bounds__(256) void scan_k(const int* __restrict__ counts, int* __restrict__ offs,
                                              const void* __restrict__ W2, const void* __restrict__ b2,
                                              const float* __restrict__ u3, float* __restrict__ u2,
                                              float* __restrict__ cp, const int* bfp){
  int blk = blockIdx.x, tid = threadIdx.x;
  if (blk == 0){
    __shared__ int part[256];
    const int CH = (NN + 255) / 256;
    int base = tid * CH, s = 0;
    for (int i = 0; i < CH; ++i){ int idx = base + i; if (idx < NN) s += counts[idx]; }
    part[tid] = s;
    __syncthreads();
    if (tid == 0){ int run = 0; for (int i = 0; i < 256; ++i){ int v = part[i]; part[i] = run; run += v; } }
    __syncthreads();
    int run = part[tid];
    for (int i = 0; i < CH; ++i){ int idx = base + i; if (idx < NN){ offs[idx] = run; run += counts[idx]; } }
    if (tid == 255) offs[NN] = run;
  } else {
    int bf = *bfp;
    __shared__ float sh[4];
    #pragma unroll 1
    for (int r = 0; r < 2; ++r){
      int ob = (blk - 1) * 2 + r;
      if (ob <= 1024){
        float s = 0;
        if (ob < 1024){ for (int j = tid; j < 512; j += 256) s += ldf(W2, (size_t)ob*512 + j, bf) * u3[j]; }
        else          { for (int j = tid; j < 512; j += 256) s += ldf(b2, j, bf) * u3[j]; }
        s = waveSum(s);
        __syncthreads();
        if ((tid & 63) == 0) sh[tid >> 6] = s;
        __syncthreads();
        if (tid == 0){ float t = sh[0]+sh[1]+sh[2]+sh[3]; if (ob < 1024) u2[ob] = t; else cp[1] = t; }
      }
    }
  }
}

// ---------- GEMM (double-buffered) + coll3 ----------
__global__ __launch_bounds__(256) void gemm_k(const u16* __restrict__ A, const u16* __restrict__ BT,
                                              u16* __restrict__ h,
                                              const void* __restrict__ W1, const void* __restrict__ b1,
                                              const float* __restrict__ u2, float* __restrict__ u1,
                                              float* __restrict__ cp, const int* bfp){
  __shared__ __align__(16) u16 sA[2][64*32];
  __shared__ __align__(16) u16 sB[2][64*32];
  __shared__ float shr[4];
  int blk = blockIdx.x, tid = threadIdx.x;
  if (blk >= 495){
    int bf = *bfp;
    #pragma unroll 1
    for (int r = 0; r < 4; ++r){
      int ob = (blk - 495) * 4 + r;
      if (ob <= 1802){
        float s = 0;
        if (ob < 1802){ for (int j = tid; j < 1024; j += 256) s += ldf(W1, (size_t)ob*1024 + j, bf) * u2[j]; }
        else          { for (int j = tid; j < 1024; j += 256) s += ldf(b1, j, bf) * u2[j]; }
        s = waveSum(s);
        __syncthreads();
        if ((tid & 63) == 0) shr[tid >> 6] = s;
        __syncthreads();
        if (tid == 0){ float t = shr[0]+shr[1]+shr[2]+shr[3]; if (ob < 1802) u1[ob] = t; else cp[2] = t; }
      }
    }
    return;
  }
  int bm = (blk % 33) * 64, bn = (blk / 33) * 64;
  int lane = tid & 63, wave = tid >> 6;
  int wm = (wave >> 1) * 32, wn = (wave & 1) * 32;
  f32x4 acc[2][2] = {};
  int srow = tid >> 2;
  int schunk = (tid & 3) ^ ((tid >> 3) & 3);
  const u16* gA = A  + (size_t)(bm + srow) * KP + schunk * 8;
  const u16* gB = BT + (size_t)(bn + srow) * KP + schunk * 8;
  int fr = lane & 15, quad = lane >> 4;
  int qs = quad ^ ((fr >> 1) & 3);
  const int KIT = KP / 32;
  GLL16(gA, &sA[0][wave * 512]);
  GLL16(gB, &sB[0][wave * 512]);
  for (int kt = 0; kt < KIT; ++kt){
    int cur = kt & 1;
    __syncthreads();
    if (kt + 1 < KIT){
      GLL16(gA + (kt + 1) * 32, &sA[cur ^ 1][wave * 512]);
      GLL16(gB + (kt + 1) * 32, &sB[cur ^ 1][wave * 512]);
    }
    bf16x8 a0 = *(const bf16x8*)&sA[cur][(wm      + fr) * 32 + qs * 8];
    bf16x8 a1 = *(const bf16x8*)&sA[cur][(wm + 16 + fr) * 32 + qs * 8];
    bf16x8 b0 = *(const bf16x8*)&sB[cur][(wn      + fr) * 32 + qs * 8];
    bf16x8 b1 = *(const bf16x8*)&sB[cur][(wn + 16 + fr) * 32 + qs * 8];
    acc[0][0] = __builtin_amdgcn_mfma_f32_16x16x32_bf16(a0, b0, acc[0][0], 0,0,0);
    acc[0][1] = __builtin_amdgcn_mfma_f32_16x16x32_bf16(a0, b1, acc[0][1], 0,0,0);
    acc[1][0] = __builtin_amdgcn_mfma_f32_16x16x32_bf16(a1, b0, acc[1][0], 0,0,0);
    acc[1][1] = __builtin_amdgcn_mfma_f32_16x16x32_bf16(a1, b1, acc[1][1], 0,0,0);
  }
  #pragma unroll
  for (int im = 0; im < 2; ++im)
    #pragma unroll
    for (int in = 0; in < 2; ++in)
      #pragma unroll
      for (int i = 0; i < 4; ++i){
        int row = bm + wm + im*16 + quad*4 + i;
        int col = bn + wn + in*16 + fr;
        if (row < NN && col < FF) h[(size_t)row * HP + col] = f2bf(acc[im][in][i]);
      }
}

// ---------- per-node attention scalars (4 nodes / block, wave per node) ----------
__global__ __launch_bounds__(256) void asd_k(const u16* __restrict__ h, const void* att_s, const void* att_d,
                                             float* a_s, float* a_d, const int* bfp){
  int bf = *bfp;
  int wv = threadIdx.x >> 6, lane = threadIdx.x & 63;
  int n = blockIdx.x * 4 + wv;
  if (n >= NN) return;
  float ss = 0, sd = 0;
  for (int f = lane; f < FF; f += 64){
    float hv = bf2f(h[(size_t)n * HP + f]);
    ss += hv * ldf(att_s, f, bf);
    sd += hv * ldf(att_d, f, bf);
  }
  ss = waveSum(ss); sd = waveSum(sd);
  if (lane == 0){ a_s[n] = ss; a_d[n] = sd; }
}

// ---------- edge pass: no-max softmax (bounded logits), denom, CSR fill ----------
__global__ __launch_bounds__(256) void edge2_k(const int* __restrict__ ei, const float* __restrict__ a_s,
                                               const float* __restrict__ a_d, float* __restrict__ denom,
                                               const int* __restrict__ offs, int* __restrict__ fill,
                                               int* __restrict__ csr_src, float* __restrict__ csr_w){
  int e = blockIdx.x * 256 + threadIdx.x;
  if (e >= ETOT) return;
  int src, dst; edgeSD(ei, e, src, dst);
  float x = a_s[src] + a_d[dst];
  float ev = x > 0.f ? x : 0.2f * x;
  float ex = expf(ev);                   // |ev| small; exp overflow needs ev>88
  atomicAdd(&denom[dst], ex);
  int pos = offs[dst] + atomicAdd(&fill[dst], 1);
  csr_src[pos] = src; csr_w[pos] = ex;
}

// ---------- aggregation (+ statsA fused): only the 1778 used rows ----------
__device__ __forceinline__ void acc8(float* a, uint4 v, float w){
  u32 arr[4] = {v.x, v.y, v.z, v.w};
  #pragma unroll
  for (int i = 0; i < 4; ++i){
    a[2*i]   += w * __uint_as_float((arr[i] & 0xFFFFu) << 16);
    a[2*i+1] += w * __uint_as_float(arr[i] & 0xFFFF0000u);
  }
}
__global__ __launch_bounds__(128) void aggr_k(const u16* __restrict__ h, const int* __restrict__ offs,
                                              const int* __restrict__ csr_src, const float* __restrict__ csr_w,
                                              const float* __restrict__ denom, const void* gat_b,
                                              const void* __restrict__ mirna,
                                              const void* lw1, const void* lb1,
                                              float* __restrict__ g, float* __restrict__ gp,
                                              float2* __restrict__ pA, const int* bfp){
  int bf = *bfp;
  int m = blockIdx.x, tid = threadIdx.x;
  int dst = m < 901 ? m : m + 282;
  int o0 = offs[dst], o1 = offs[dst + 1];
  float inv = 1.0f / denom[dst];
  __shared__ int   sS[128];
  __shared__ float sW[128];
  __shared__ float red[4][2];
  const int c = tid;
  float a[8] = {0,0,0,0,0,0,0,0};
  for (int base = o0; base < o1; base += 128){
    int nb = min(128, o1 - base);
    __syncthreads();
    if (tid < nb){ sS[tid] = csr_src[base + tid]; sW[tid] = csr_w[base + tid] * inv; }
    __syncthreads();
    if (c < 113){
      int k = 0;
      for (; k + 4 <= nb; k += 4){
        int   i0 = sS[k], i1 = sS[k+1], i2 = sS[k+2], i3 = sS[k+3];
        float w0 = sW[k], w1 = sW[k+1], w2 = sW[k+2], w3 = sW[k+3];
        uint4 v0 = ((const uint4*)(h + (size_t)i0 * HP))[c];
        uint4 v1 = ((const uint4*)(h + (size_t)i1 * HP))[c];
        uint4 v2 = ((const uint4*)(h + (size_t)i2 * HP))[c];
        uint4 v3 = ((const uint4*)(h + (size_t)i3 * HP))[c];
        acc8(a, v0, w0); acc8(a, v1, w1); acc8(a, v2, w2); acc8(a, v3, w3);
      }
      for (; k < nb; ++k){
        uint4 v0 = ((const uint4*)(h + (size_t)sS[k] * HP))[c];
        acc8(a, v0, sW[k]);
      }
    }
  }
  float w00 = ldf(lw1,0,bf), w01 = ldf(lw1,1,bf), bb = ldf(lb1,0,bf);
  float sx0 = 0, sx1 = 0, sl = 0, sl2 = 0;
  if (c < 113){
    int f0 = 8 * c;
    float r[8];
    #pragma unroll
    for (int i = 0; i < 8; ++i){
      bool inb = (f0 + i) < FF;
      float v = a[i] + (inb ? ldf(gat_b, f0 + i, bf) : 0.f);
      v = v > 0.f ? v : 0.f;
      r[i] = inb ? v : 0.f;
      if (inb){
        float x1 = ldf(mirna, (size_t)m * FF + f0 + i, bf);
        float xl = w00*r[i] + w01*x1 + bb;
        sx0 += r[i]; sx1 += x1; sl += xl; sl2 += xl*xl;
      }
    }
    float4* go = (float4*)(g + (size_t)dst * HP);
    go[2*c]   = make_float4(r[0], r[1], r[2], r[3]);
    go[2*c+1] = make_float4(r[4], r[5], r[6], r[7]);
  }
  sx0 = waveSum(sx0); sx1 = waveSum(sx1); sl = waveSum(sl); sl2 = waveSum(sl2);
  int wv = tid >> 6;
  if ((tid & 63) == 0){ red[0][wv]=sx0; red[1][wv]=sx1; red[2][wv]=sl; red[3][wv]=sl2; }
  __syncthreads();
  if (tid == 0){
    gp[2*m]   = (red[0][0]+red[0][1]) / (float)FF;
    gp[2*m+1] = (red[1][0]+red[1][1]) / (float)FF;
    pA[m] = make_float2(red[2][0]+red[2][1], red[3][0]+red[3][1]);
  }
}

// ---------- bn_k: blocks 0..MM-1 = statsB (local pA reduce, no dependency); block MM = xg ----------
__global__ __launch_bounds__(256) void bn_k(const float* __restrict__ g, const void* __restrict__ mirna,
                                            const void* lw1, const void* lb1,
                                            const void* gw1, const void* gb1, const void* gw2,
                                            const float* __restrict__ gp,
                                            const float2* __restrict__ pA, float2* __restrict__ pB,
                                            float* __restrict__ xg2b, const int* bfp){
  __shared__ float xs[MM];
  __shared__ float red[2][4];
  __shared__ float bc[3];
  int m = blockIdx.x, tid = threadIdx.x, bf = *bfp;
  int wv = tid >> 6;
  if (m == MM){
    // ---- xg branch (gp -> xg2b), self-contained ----
    float g10 = ldf(gw1,0,bf), g11 = ldf(gw1,1,bf), b1v = ldf(gb1,0,bf);
    float s = 0, s2 = 0;
    for (int i = tid; i < MM; i += 256){
      float v = g10*gp[2*i] + g11*gp[2*i+1] + b1v;
      xs[i] = v; s += v; s2 += v*v;
    }
    s = waveSum(s); s2 = waveSum(s2);
    if ((tid & 63) == 0){ red[0][wv] = s; red[1][wv] = s2; }
    __syncthreads();
    if (tid == 0){
      float t  = red[0][0]+red[0][1]+red[0][2]+red[0][3];
      float t2 = red[1][0]+red[1][1]+red[1][2]+red[1][3];
      float mean = t / (float)MM, var = t2 / (float)MM - mean*mean;
      bc[0] = mean; bc[1] = rsqrtf(var + EPSV);
    }
    __syncthreads();
    float mean = bc[0], rs = bc[1];
    s = 0; s2 = 0;
    for (int i = tid; i < MM; i += 256){
      float r = (xs[i] - mean) * rs; r = r > 0.f ? r : 0.f;
      xs[i] = r; s += r; s2 += r*r;
    }
    s = waveSum(s); s2 = waveSum(s2);
    __syncthreads();
    if ((tid & 63) == 0){ red[0][wv] = s; red[1][wv] = s2; }
    __syncthreads();
    if (tid == 0){
      float t  = red[0][0]+red[0][1]+red[0][2]+red[0][3];
      float t2 = red[1][0]+red[1][1]+red[1][2]+red[1][3];
      float mrg = t / (float)MM, vrg = t2 / (float)MM - mrg*mrg;
      float g20 = ldf(gw2,0,bf), g21 = ldf(gw2,1,bf);
      bc[0] = mrg;
      bc[1] = g20 * rsqrtf(g20*g20*vrg + EPSV);
      bc[2] = g21 * rsqrtf(g21*g21*vrg + EPSV);
    }
    __syncthreads();
    float mrg = bc[0], c0 = bc[1], c1 = bc[2];
    for (int i = tid; i < MM; i += 256){
      float d = xs[i] - mrg;
      xg2b[2*i] = c0 * d; xg2b[2*i+1] = c1 * d;
    }
  } else {
    // ---- local pA reduction -> mu1, rs1 (no cross-block dependency) ----
    float s = 0, s2 = 0;
    for (int i = tid; i < MM; i += 256){ float2 p = pA[i]; s += p.x; s2 += p.y; }
    s = waveSum(s); s2 = waveSum(s2);
    if ((tid & 63) == 0){ red[0][wv] = s; red[1][wv] = s2; }
    __syncthreads();
    if (tid == 0){
      float t  = red[0][0]+red[0][1]+red[0][2]+red[0][3];
      float t2 = red[1][0]+red[1][1]+red[1][2]+red[1][3];
      float mu = (float)((double)t / NTOT);
      bc[0] = mu;
      bc[1] = rsqrtf((float)((double)t2 / NTOT) - mu*mu + EPSV);
    }
    __syncthreads();
    float mu1 = bc[0], rs1 = bc[1];
    // ---- statsB row ----
    int gr = m < 901 ? m : m + 282;
    float w00 = ldf(lw1,0,bf), w01 = ldf(lw1,1,bf), bb = ldf(lb1,0,bf);
    float sr = 0, sr2 = 0;
    for (int w = tid; w < FF; w += 256){
      float x0 = g[(size_t)gr * HP + w];
      float x1 = ldf(mirna, (size_t)m * FF + w, bf);
      float xl = w00*x0 + w01*x1 + bb;
      float r = (xl - mu1) * rs1; r = r > 0.f ? r : 0.f;
      sr += r; sr2 += r*r;
    }
    sr = waveSum(sr); sr2 = waveSum(sr2);
    __syncthreads();
    if ((tid & 63) == 0){ red[0][wv] = sr; red[1][wv] = sr2; }
    __syncthreads();
    if (tid == 0) pB[m] = make_float2(red[0][0]+red[0][1]+red[0][2]+red[0][3],
                                      red[1][0]+red[1][1]+red[1][2]+red[1][3]);
  }
}

// ---------- fs_k: local pA+pB reductions, then fused row -> s0/s1 dot ----------
__global__ __launch_bounds__(256) void fs_k(const float* __restrict__ g, const void* __restrict__ mirna,
                                            const void* lw1, const void* lb1, const void* lw2,
                                            const float2* __restrict__ pA, const float2* __restrict__ pB,
                                            const float* __restrict__ xg2b,
                                            const float* __restrict__ u1,
                                            float* __restrict__ s0, float* __restrict__ s1, const int* bfp){
  __shared__ float red[4][4];
  __shared__ float cst[5];   // mu1, rs1, mr, A0, A1
  int bf = *bfp;
  int m = blockIdx.x, tid = threadIdx.x;
  int wv = tid >> 6;
  // local reductions of pA and pB
  {
    float a1 = 0, a2 = 0, b1 = 0, b2 = 0;
    for (int i = tid; i < MM; i += 256){
      float2 p = pA[i]; a1 += p.x; a2 += p.y;
      float2 q = pB[i]; b1 += q.x; b2 += q.y;
    }
    a1 = waveSum(a1); a2 = waveSum(a2); b1 = waveSum(b1); b2 = waveSum(b2);
    if ((tid & 63) == 0){ red[0][wv]=a1; red[1][wv]=a2; red[2][wv]=b1; red[3][wv]=b2; }
    __syncthreads();
    if (tid == 0){
      float tA  = red[0][0]+red[0][1]+red[0][2]+red[0][3];
      float tA2 = red[1][0]+red[1][1]+red[1][2]+red[1][3];
      float tB  = red[2][0]+red[2][1]+red[2][2]+red[2][3];
      float tB2 = red[3][0]+red[3][1]+red[3][2]+red[3][3];
      float mu = (float)((double)tA / NTOT);
      float rs = rsqrtf((float)((double)tA2 / NTOT) - mu*mu + EPSV);
      float mr = (float)((double)tB / NTOT);
      float vr = (float)((double)tB2 / NTOT) - mr*mr;
      float l20 = ldf(lw2,0,bf), l21 = ldf(lw2,1,bf);
      cst[0] = mu; cst[1] = rs; cst[2] = mr;
      cst[3] = l20 * rsqrtf(l20*l20*vr + EPSV);
      cst[4] = l21 * rsqrtf(l21*l21*vr + EPSV);
    }
    __syncthreads();
  }
  float mu1 = cst[0], rs1 = cst[1], mr = cst[2], A0 = cst[3], A1 = cst[4];
  int gr = m < 901 ? m : m + 282;
  float w00 = ldf(lw1,0,bf), w01 = ldf(lw1,1,bf), bb = ldf(lb1,0,bf);
  float xa = xg2b[2*m], xb = xg2b[2*m+1];
  float p0 = 0, p1 = 0;
  for (int w = tid; w < FF; w += 256){
    float x0 = g[(size_t)gr * HP + w];
    float x1 = ldf(mirna, (size_t)m * FF + w, bf);
    float xl = w00*x0 + w01*x1 + bb;
    float r = (xl - mu1) * rs1; r = r > 0.f ? r : 0.f;
    float rc = r - mr;
    float z0 = A0*rc + xa, z1 = A1*rc + xb;
    float sg0 = 1.f / (1.f + expf(-z0));
    float sg1 = 1.f / (1.f + expf(-z1));
    float f = 0.5f * (x0*sg0 + x1*sg1);
    p0 += f * u1[w]; p1 += f * u1[901 + w];
  }
  p0 = waveSum(p0); p1 = waveSum(p1);
  __syncthreads();
  if ((tid & 63) == 0){ red[0][wv] = p0; red[1][wv] = p1; }
  __syncthreads();
  if (tid == 0){
    s0[m] = red[0][0]+red[0][1]+red[0][2]+red[0][3];
    s1[m] = red[1][0]+red[1][1]+red[1][2]+red[1][3];
  }
}

// ---------- final scores ----------
__global__ __launch_bounds__(256) void out_k(const int* __restrict__ tr, const int* __restrict__ te,
                                             const float* __restrict__ s0, const float* __restrict__ s1,
                                             const float* __restrict__ cp, void* __restrict__ out,
                                             const int* bfp){
  int bf = *bfp;
  int b = blockIdx.x * 256 + threadIdx.x;
  if (b >= NOUT) return;
  int i, j;
  if (b < NTR){ i = tr[2*b]; j = tr[2*b + 1]; }
  else { int t = b - NTR; i = te[2*t]; j = te[2*t + 1]; }
  float z = s0[i] + s1[j] + cp[0] + cp[1] + cp[2];
  float v = 1.f / (1.f + expf(-z));
  if (bf) ((u16*)out)[b] = f2bf(v);
  else    ((float*)out)[b] = v;
}

extern "C" void kernel_launch(void* const* d_in, const int* in_sizes, int n_in,
                              void* d_out, int out_size, void* d_ws, size_t ws_size,
                              hipStream_t stream){
  const void* x_feat = d_in[0];
  const void* mirna  = d_in[1];
  const void* Wg     = d_in[2];
  const void* att_s  = d_in[3];
  const void* att_d  = d_in[4];
  const void* gat_b  = d_in[5];
  const void* lw1    = d_in[6];
  const void* lb1    = d_in[7];
  const void* lw2    = d_in[8];
  const void* gw1    = d_in[10];
  const void* gb1    = d_in[11];
  const void* gw2    = d_in[12];
  const void* W1     = d_in[14];
  const void* b1     = d_in[15];
  const void* W2     = d_in[16];
  const void* b2     = d_in[17];
  const void* W3     = d_in[18];
  const void* b3     = d_in[19];
  const void* W4     = d_in[20];
  const void* b4     = d_in[21];
  const int* ei      = (const int*)d_in[22];
  const int* tr      = (const int*)d_in[23];
  const int* te      = (const int*)d_in[24];

  char* ws = (char*)d_ws;
  size_t off = 0;
  auto alloc = [&](size_t bytes)->size_t{ size_t o = off; off += (bytes + 255) & ~(size_t)255; return o; };
  size_t oA  = alloc((size_t)MP*KP*2);     // padded A; later overlaid by g [NN][HP] f32
  size_t oBT = alloc((size_t)NP*KP*2);
  size_t oH  = alloc((size_t)NN*HP*2);     // h bf16, padded stride
  size_t oCS = alloc((size_t)ETOT*4);
  size_t oCW = alloc((size_t)ETOT*4);
  size_t oAS = alloc(NN*4);
  size_t oAD = alloc(NN*4);
  size_t oOF = alloc((NN+1)*4);
  size_t oGP = alloc(MM*2*4);
  size_t oXG = alloc(MM*2*4);
  size_t oS0 = alloc(MM*4);
  size_t oS1 = alloc(MM*4);
  size_t oU3 = alloc(512*4);
  size_t oU2 = alloc(1024*4);
  size_t oU1 = alloc(1802*4);
  size_t oPA = alloc(MM*8);
  size_t oPB = alloc(MM*8);
  size_t oCP = alloc(3*4);
  size_t oBF = alloc(4);
  size_t zstart = off;                     // ---- zeroed region ----
  size_t oCT = alloc(NN*4);                // counts
  size_t oFL = alloc(NN*4);                // fill
  size_t oDN = alloc(NN*4);                // denom
  size_t zend = off;

  u16*   Ap   = (u16*)(ws+oA);
  u16*   BT   = (u16*)(ws+oBT);
  u16*   h    = (u16*)(ws+oH);
  float* gbuf = (float*)(ws+oA);           // overlay: A dead after gemm
  int*   csrS = (int*)(ws+oCS);
  float* csrW = (float*)(ws+oCW);
  float* a_s  = (float*)(ws+oAS);
  float* a_d  = (float*)(ws+oAD);
  int*   offs = (int*)(ws+oOF);
  float* gp   = (float*)(ws+oGP);
  float* xg2b = (float*)(ws+oXG);
  float* s0   = (float*)(ws+oS0);
  float* s1   = (float*)(ws+oS1);
  float* u3   = (float*)(ws+oU3);
  float* u2   = (float*)(ws+oU2);
  float* u1   = (float*)(ws+oU1);
  float2* pA  = (float2*)(ws+oPA);
  float2* pB  = (float2*)(ws+oPB);
  float* cp   = (float*)(ws+oCP);
  int*   bfp  = (int*)(ws+oBF);
  int*   cnts = (int*)(ws+oCT);
  int*   fill = (int*)(ws+oFL);
  float* denom= (float*)(ws+oDN);

  hipMemsetAsync(ws + zstart, 0, zend - zstart, stream);

  pad_k  <<<MP + 1950 + 514 + (ETOT+255)/256, 256, 0, stream>>>(
      x_feat, Wg, W3, W4, b3, b4, ei, Ap, BT, u3, cp, cnts, bfp);
  scan_k <<<514, 256, 0, stream>>>(cnts, offs, W2, b2, u3, u2, cp, bfp);
  gemm_k <<<495 + 451, 256, 0, stream>>>(Ap, BT, h, W1, b1, u2, u1, cp, bfp);
  asd_k  <<<(NN+3)/4, 256, 0, stream>>>(h, att_s, att_d, a_s, a_d, bfp);
  edge2_k<<<(ETOT+255)/256, 256, 0, stream>>>(ei, a_s, a_d, denom, offs, fill, csrS, csrW);
  aggr_k <<<MM, 128, 0, stream>>>(h, offs, csrS, csrW, denom, gat_b, mirna, lw1, lb1, gbuf, gp, pA, bfp);
  bn_k   <<<MM + 1, 256, 0, stream>>>(gbuf, mirna, lw1, lb1, gw1, gb1, gw2, gp, pA, pB, xg2b, bfp);
  fs_k   <<<MM, 256, 0, stream>>>(gbuf, mirna, lw1, lb1, lw2, pA, pB, xg2b, u1, s0, s1, bfp);
  out_k  <<<(NOUT+255)/256, 256, 0, stream>>>(tr, te, s0, s1, cp, d_out, bfp);
}

// Round 12
// 250.676 us; speedup vs baseline: 1.8952x; 1.0163x over previous
//
#include <hip/hip_runtime.h>

typedef unsigned short u16;
typedef unsigned int   u32;

#define NN   2060          // graph nodes
#define FF   901           // feature dim
#define HP   904           // padded row stride for h (bf16) / g (f32)
#define MM   1778          // fused rows
#define EE   131840        // edges (w/o self loops)
#define ETOT 133900        // edges + self loops
#define NTR  100000
#define NOUT 130000
#define MP   2112          // padded M (33*64)
#define KP   2080          // padded K (65*32)
#define NP   960           // padded N (15*64)
#define EPSV 1e-5f
#define NTOT 1601978.0     // MM*FF

typedef __attribute__((ext_vector_type(4))) float f32x4;
typedef __attribute__((ext_vector_type(8))) short bf16x8;

#define GLL16(g,l) __builtin_amdgcn_global_load_lds( \
    (const __attribute__((address_space(1))) u32*)(g), \
    (__attribute__((address_space(3))) u32*)(l), 16, 0, 0)

__device__ __forceinline__ float bf2f(u16 u){ return __uint_as_float(((u32)u)<<16); }
__device__ __forceinline__ u16 f2bf(float f){
  u32 b = __float_as_uint(f);
  return (u16)((b + 0x7fffu + ((b>>16)&1u)) >> 16);
}
__device__ __forceinline__ float ldf(const void* p, size_t i, int bf){
  return bf ? bf2f(((const u16*)p)[i]) : ((const float*)p)[i];
}
__device__ __forceinline__ u16 ldb(const void* p, size_t i, int bf){
  return bf ? ((const u16*)p)[i] : f2bf(((const float*)p)[i]);
}
__device__ __forceinline__ float waveSum(float v){
  #pragma unroll
  for (int o = 32; o; o >>= 1) v += __shfl_down(v, o);
  return v;
}
__device__ __forceinline__ int waveSumI(int v){
  #pragma unroll
  for (int o = 32; o; o >>= 1) v += __shfl_down(v, o);
  return v;
}
__device__ __forceinline__ int flagWave(const u32* __restrict__ x){
  int l = threadIdx.x & 63;
  u32 w0 = x[l], w1 = x[l + 64];
  int big = (((w0 >> 7)  & 0xFFu) >= 0xC0u) + (((w0 >> 23) & 0xFFu) >= 0xC0u)
          + (((w1 >> 7)  & 0xFFu) >= 0xC0u) + (((w1 >> 23) & 0xFFu) >= 0xC0u);
  big = waveSumI(big);
  return (__shfl(big, 0) >= 8) ? 0 : 1;
}
__device__ __forceinline__ void edgeSD(const int* __restrict__ ei, int e, int& src, int& dst){
  if (e < EE){ src = ei[e]; dst = ei[EE + e]; } else { src = dst = e - EE; }
}

// pad_k grid segments
#define SB_TR   MP                 // 2112: transpose
#define SB_C1   (MP + 1950)        // 4062: coll1
#define SB_WV   (SB_C1 + 514)      // 4576: wsv/wdv (Wg @ att_{s,d})
#define SB_ED   (SB_WV + 515)      // 5091: edge counting
#define PAD_GRID (SB_ED + 524)     // 5615

// ---------- fused prep: A-pad(vec8) | Wg transpose | coll1 | wsv gemv | edge counting ----------
__global__ __launch_bounds__(256) void pad_k(const void* __restrict__ X, const void* __restrict__ Wg,
                                             const void* __restrict__ W3, const void* __restrict__ W4,
                                             const void* __restrict__ b3, const void* __restrict__ b4,
                                             const void* __restrict__ att_s, const void* __restrict__ att_d,
                                             const int* __restrict__ ei,
                                             u16* __restrict__ Ap, u16* __restrict__ BT,
                                             float* __restrict__ u3, float* __restrict__ cp,
                                             float* __restrict__ wsv, float* __restrict__ wdv,
                                             int* __restrict__ cnts, int* bfp){
  __shared__ u16 tt[32][33];
  int bf = flagWave((const u32*)X);
  int blk = blockIdx.x, tid = threadIdx.x;
  if (blk == 0 && tid == 0) *bfp = bf;
  if (blk < MP){
    int row = blk;
    for (int c0 = tid * 8; c0 < KP; c0 += 2048){
      u16 v[8] = {0,0,0,0,0,0,0,0};
      if (row < NN){
        if (c0 + 8 <= NN){
          if (bf){
            ushort4 t0 = *(const ushort4*)((const u16*)X + (size_t)row * NN + c0);
            ushort4 t1 = *(const ushort4*)((const u16*)X + (size_t)row * NN + c0 + 4);
            v[0]=t0.x; v[1]=t0.y; v[2]=t0.z; v[3]=t0.w;
            v[4]=t1.x; v[5]=t1.y; v[6]=t1.z; v[7]=t1.w;
          } else {
            float4 t0 = *(const float4*)((const float*)X + (size_t)row * NN + c0);
            float4 t1 = *(const float4*)((const float*)X + (size_t)row * NN + c0 + 4);
            v[0]=f2bf(t0.x); v[1]=f2bf(t0.y); v[2]=f2bf(t0.z); v[3]=f2bf(t0.w);
            v[4]=f2bf(t1.x); v[5]=f2bf(t1.y); v[6]=f2bf(t1.z); v[7]=f2bf(t1.w);
          }
        } else {
          #pragma unroll
          for (int i = 0; i < 8; ++i)
            if (c0 + i < NN) v[i] = ldb(X, (size_t)row * NN + c0 + i, bf);
        }
      }
      *(uint4*)(Ap + (size_t)row * KP + c0) = *(const uint4*)v;
    }
  } else if (blk < SB_C1){
    int t = blk - SB_TR;
    int kb = (t % 65) * 32, nb = (t / 65) * 32;
    int tx = tid & 31, ty = tid >> 5;
    #pragma unroll
    for (int i = 0; i < 4; ++i){
      int k = kb + ty + 8*i, n = nb + tx;
      u16 v = 0;
      if (k < NN && n < FF) v = ldb(Wg, (size_t)k * FF + n, bf);
      tt[ty + 8*i][tx] = v;
    }
    __syncthreads();
    #pragma unroll
    for (int i = 0; i < 4; ++i){
      int n = nb + ty + 8*i, k = kb + tx;
      if (n < NP && k < KP) BT[(size_t)n * KP + k] = tt[tx][ty + 8*i];
    }
  } else if (blk < SB_WV){
    if (tid >= 64) return;
    int ob = blk - SB_C1;
    if (ob > 512) return;
    float s = (ob < 512) ? ldf(W3, (size_t)ob*64 + tid, bf) * ldf(W4, tid, bf)
                         : ldf(b3, tid, bf) * ldf(W4, tid, bf);
    s = waveSum(s);
    if (tid == 0){ if (ob < 512) u3[ob] = s; else cp[0] = s + ldf(b4, 0, bf); }
  } else if (blk < SB_ED){
    // wsv[k] = Wg[k,:] . att_s ; wdv[k] = Wg[k,:] . att_d   (wave per k, 4 k/block)
    int wv = tid >> 6, lane = tid & 63;
    int k = (blk - SB_WV) * 4 + wv;
    if (k >= NN) return;
    float ss = 0, sd = 0;
    for (int c = lane; c < FF; c += 64){
      float w = ldf(Wg, (size_t)k * FF + c, bf);
      ss += w * ldf(att_s, c, bf);
      sd += w * ldf(att_d, c, bf);
    }
    ss = waveSum(ss); sd = waveSum(sd);
    if (lane == 0){ wsv[k] = ss; wdv[k] = sd; }
  } else {
    int e = (blk - SB_ED) * 256 + tid;
    if (e >= ETOT) return;
    int src, dst; edgeSD(ei, e, src, dst);
    atomicAdd(&cnts[dst], 1);
  }
}

// ---------- scan (block 0) + coll2 (1..513) + attention-scalar GEMV (514..1028) ----------
__global__ __launch_bounds__(256) void scan_k(const int* __restrict__ counts, int* __restrict__ offs,
                                              const void* __restrict__ W2, const void* __restrict__ b2,
                                              const float* __restrict__ u3, float* __restrict__ u2,
                                              float* __restrict__ cp,
                                              const u16* __restrict__ Ap,
                                              const float* __restrict__ wsv, const float* __restrict__ wdv,
                                              float* __restrict__ a_s, float* __restrict__ a_d,
                                              const int* bfp){
  int blk = blockIdx.x, tid = threadIdx.x;
  if (blk == 0){
    __shared__ int part[256];
    const int CH = (NN + 255) / 256;
    int base = tid * CH, s = 0;
    for (int i = 0; i < CH; ++i){ int idx = base + i; if (idx < NN) s += counts[idx]; }
    part[tid] = s;
    __syncthreads();
    if (tid == 0){ int run = 0; for (int i = 0; i < 256; ++i){ int v = part[i]; part[i] = run; run += v; } }
    __syncthreads();
    int run = part[tid];
    for (int i = 0; i < CH; ++i){ int idx = base + i; if (idx < NN){ offs[idx] = run; run += counts[idx]; } }
    if (tid == 255) offs[NN] = run;
  } else if (blk < 514){
    int bf = *bfp;
    __shared__ float sh[4];
    #pragma unroll 1
    for (int r = 0; r < 2; ++r){
      int ob = (blk - 1) * 2 + r;
      if (ob <= 1024){
        float s = 0;
        if (ob < 1024){ for (int j = tid; j < 512; j += 256) s += ldf(W2, (size_t)ob*512 + j, bf) * u3[j]; }
        else          { for (int j = tid; j < 512; j += 256) s += ldf(b2, j, bf) * u3[j]; }
        s = waveSum(s);
        __syncthreads();
        if ((tid & 63) == 0) sh[tid >> 6] = s;
        __syncthreads();
        if (tid == 0){ float t = sh[0]+sh[1]+sh[2]+sh[3]; if (ob < 1024) u2[ob] = t; else cp[1] = t; }
      }
    }
  } else {
    // a_s[n] = Ap[n,:] . wsv ; a_d[n] = Ap[n,:] . wdv   (wave per node, 4 nodes/block)
    int wv = tid >> 6, lane = tid & 63;
    int n = (blk - 514) * 4 + wv;
    if (n >= NN) return;
    const u16* row = Ap + (size_t)n * KP;
    float ss = 0, sd = 0;
    for (int k0 = lane * 8; k0 < KP; k0 += 512){
      uint4 v = *(const uint4*)(row + k0);            // 8 bf16 (zero-padded cols)
      float4 w0 = *(const float4*)(wsv + k0);
      float4 w1 = *(const float4*)(wsv + k0 + 4);
      float4 d0 = *(const float4*)(wdv + k0);
      float4 d1 = *(const float4*)(wdv + k0 + 4);
      u32 arr[4] = {v.x, v.y, v.z, v.w};
      float xv[8];
      #pragma unroll
      for (int i = 0; i < 4; ++i){
        xv[2*i]   = __uint_as_float((arr[i] & 0xFFFFu) << 16);
        xv[2*i+1] = __uint_as_float(arr[i] & 0xFFFF0000u);
      }
      ss += xv[0]*w0.x + xv[1]*w0.y + xv[2]*w0.z + xv[3]*w0.w
          + xv[4]*w1.x + xv[5]*w1.y + xv[6]*w1.z + xv[7]*w1.w;
      sd += xv[0]*d0.x + xv[1]*d0.y + xv[2]*d0.z + xv[3]*d0.w
          + xv[4]*d1.x + xv[5]*d1.y + xv[6]*d1.z + xv[7]*d1.w;
    }
    ss = waveSum(ss); sd = waveSum(sd);
    if (lane == 0){ a_s[n] = ss; a_d[n] = sd; }
  }
}

// ---------- GEMM (double-buffered) + coll3 ----------
__global__ __launch_bounds__(256) void gemm_k(const u16* __restrict__ A, const u16* __restrict__ BT,
                                              u16* __restrict__ h,
                                              const void* __restrict__ W1, const void* __restrict__ b1,
                                              const float* __restrict__ u2, float* __restrict__ u1,
                                              float* __restrict__ cp, const int* bfp){
  __shared__ __align__(16) u16 sA[2][64*32];
  __shared__ __align__(16) u16 sB[2][64*32];
  __shared__ float shr[4];
  int blk = blockIdx.x, tid = threadIdx.x;
  if (blk >= 495){
    int bf = *bfp;
    #pragma unroll 1
    for (int r = 0; r < 4; ++r){
      int ob = (blk - 495) * 4 + r;
      if (ob <= 1802){
        float s = 0;
        if (ob < 1802){ for (int j = tid; j < 1024; j += 256) s += ldf(W1, (size_t)ob*1024 + j, bf) * u2[j]; }
        else          { for (int j = tid; j < 1024; j += 256) s += ldf(b1, j, bf) * u2[j]; }
        s = waveSum(s);
        __syncthreads();
        if ((tid & 63) == 0) shr[tid >> 6] = s;
        __syncthreads();
        if (tid == 0){ float t = shr[0]+shr[1]+shr[2]+shr[3]; if (ob < 1802) u1[ob] = t; else cp[2] = t; }
      }
    }
    return;
  }
  int bm = (blk % 33) * 64, bn = (blk / 33) * 64;
  int lane = tid & 63, wave = tid >> 6;
  int wm = (wave >> 1) * 32, wn = (wave & 1) * 32;
  f32x4 acc[2][2] = {};
  int srow = tid >> 2;
  int schunk = (tid & 3) ^ ((tid >> 3) & 3);
  const u16* gA = A  + (size_t)(bm + srow) * KP + schunk * 8;
  const u16* gB = BT + (size_t)(bn + srow) * KP + schunk * 8;
  int fr = lane & 15, quad = lane >> 4;
  int qs = quad ^ ((fr >> 1) & 3);
  const int KIT = KP / 32;
  GLL16(gA, &sA[0][wave * 512]);
  GLL16(gB, &sB[0][wave * 512]);
  for (int kt = 0; kt < KIT; ++kt){
    int cur = kt & 1;
    __syncthreads();
    if (kt + 1 < KIT){
      GLL16(gA + (kt + 1) * 32, &sA[cur ^ 1][wave * 512]);
      GLL16(gB + (kt + 1) * 32, &sB[cur ^ 1][wave * 512]);
    }
    bf16x8 a0 = *(const bf16x8*)&sA[cur][(wm      + fr) * 32 + qs * 8];
    bf16x8 a1 = *(const bf16x8*)&sA[cur][(wm + 16 + fr) * 32 + qs * 8];
    bf16x8 b0 = *(const bf16x8*)&sB[cur][(wn      + fr) * 32 + qs * 8];
    bf16x8 b1 = *(const bf16x8*)&sB[cur][(wn + 16 + fr) * 32 + qs * 8];
    acc[0][0] = __builtin_amdgcn_mfma_f32_16x16x32_bf16(a0, b0, acc[0][0], 0,0,0);
    acc[0][1] = __builtin_amdgcn_mfma_f32_16x16x32_bf16(a0, b1, acc[0][1], 0,0,0);
    acc[1][0] = __builtin_amdgcn_mfma_f32_16x16x32_bf16(a1, b0, acc[1][0], 0,0,0);
    acc[1][1] = __builtin_amdgcn_mfma_f32_16x16x32_bf16(a1, b1, acc[1][1], 0,0,0);
  }
  #pragma unroll
  for (int im = 0; im < 2; ++im)
    #pragma unroll
    for (int in = 0; in < 2; ++in)
      #pragma unroll
      for (int i = 0; i < 4; ++i){
        int row = bm + wm + im*16 + quad*4 + i;
        int col = bn + wn + in*16 + fr;
        if (row < NN && col < FF) h[(size_t)row * HP + col] = f2bf(acc[im][in][i]);
      }
}

// ---------- edge pass: no-max softmax (bounded logits), denom, CSR fill ----------
__global__ __launch_bounds__(256) void edge2_k(const int* __restrict__ ei, const float* __restrict__ a_s,
                                               const float* __restrict__ a_d, float* __restrict__ denom,
                                               const int* __restrict__ offs, int* __restrict__ fill,
                                               int* __restrict__ csr_src, float* __restrict__ csr_w){
  int e = blockIdx.x * 256 + threadIdx.x;
  if (e >= ETOT) return;
  int src, dst; edgeSD(ei, e, src, dst);
  float x = a_s[src] + a_d[dst];
  float ev = x > 0.f ? x : 0.2f * x;
  float ex = expf(ev);                   // |ev| small; exp overflow needs ev>88
  atomicAdd(&denom[dst], ex);
  int pos = offs[dst] + atomicAdd(&fill[dst], 1);
  csr_src[pos] = src; csr_w[pos] = ex;
}

// ---------- aggregation (+ statsA fused): only the 1778 used rows ----------
__device__ __forceinline__ void acc8(float* a, uint4 v, float w){
  u32 arr[4] = {v.x, v.y, v.z, v.w};
  #pragma unroll
  for (int i = 0; i < 4; ++i){
    a[2*i]   += w * __uint_as_float((arr[i] & 0xFFFFu) << 16);
    a[2*i+1] += w * __uint_as_float(arr[i] & 0xFFFF0000u);
  }
}
__global__ __launch_bounds__(128) void aggr_k(const u16* __restrict__ h, const int* __restrict__ offs,
                                              const int* __restrict__ csr_src, const float* __restrict__ csr_w,
                                              const float* __restrict__ denom, const void* gat_b,
                                              const void* __restrict__ mirna,
                                              const void* lw1, const void* lb1,
                                              float* __restrict__ g, float* __restrict__ gp,
                                              float2* __restrict__ pA, const int* bfp){
  int bf = *bfp;
  int m = blockIdx.x, tid = threadIdx.x;
  int dst = m < 901 ? m : m + 282;
  int o0 = offs[dst], o1 = offs[dst + 1];
  float inv = 1.0f / denom[dst];
  __shared__ int   sS[128];
  __shared__ float sW[128];
  __shared__ float red[4][2];
  const int c = tid;
  float a[8] = {0,0,0,0,0,0,0,0};
  for (int base = o0; base < o1; base += 128){
    int nb = min(128, o1 - base);
    __syncthreads();
    if (tid < nb){ sS[tid] = csr_src[base + tid]; sW[tid] = csr_w[base + tid] * inv; }
    __syncthreads();
    if (c < 113){
      int k = 0;
      for (; k + 4 <= nb; k += 4){
        int   i0 = sS[k], i1 = sS[k+1], i2 = sS[k+2], i3 = sS[k+3];
        float w0 = sW[k], w1 = sW[k+1], w2 = sW[k+2], w3 = sW[k+3];
        uint4 v0 = ((const uint4*)(h + (size_t)i0 * HP))[c];
        uint4 v1 = ((const uint4*)(h + (size_t)i1 * HP))[c];
        uint4 v2 = ((const uint4*)(h + (size_t)i2 * HP))[c];
        uint4 v3 = ((const uint4*)(h + (size_t)i3 * HP))[c];
        acc8(a, v0, w0); acc8(a, v1, w1); acc8(a, v2, w2); acc8(a, v3, w3);
      }
      for (; k < nb; ++k){
        uint4 v0 = ((const uint4*)(h + (size_t)sS[k] * HP))[c];
        acc8(a, v0, sW[k]);
      }
    }
  }
  float w00 = ldf(lw1,0,bf), w01 = ldf(lw1,1,bf), bb = ldf(lb1,0,bf);
  float sx0 = 0, sx1 = 0, sl = 0, sl2 = 0;
  if (c < 113){
    int f0 = 8 * c;
    float r[8];
    #pragma unroll
    for (int i = 0; i < 8; ++i){
      bool inb = (f0 + i) < FF;
      float v = a[i] + (inb ? ldf(gat_b, f0 + i, bf) : 0.f);
      v = v > 0.f ? v : 0.f;
      r[i] = inb ? v : 0.f;
      if (inb){
        float x1 = ldf(mirna, (size_t)m * FF + f0 + i, bf);
        float xl = w00*r[i] + w01*x1 + bb;
        sx0 += r[i]; sx1 += x1; sl += xl; sl2 += xl*xl;
      }
    }
    float4* go = (float4*)(g + (size_t)dst * HP);
    go[2*c]   = make_float4(r[0], r[1], r[2], r[3]);
    go[2*c+1] = make_float4(r[4], r[5], r[6], r[7]);
  }
  sx0 = waveSum(sx0); sx1 = waveSum(sx1); sl = waveSum(sl); sl2 = waveSum(sl2);
  int wv = tid >> 6;
  if ((tid & 63) == 0){ red[0][wv]=sx0; red[1][wv]=sx1; red[2][wv]=sl; red[3][wv]=sl2; }
  __syncthreads();
  if (tid == 0){
    gp[2*m]   = (red[0][0]+red[0][1]) / (float)FF;
    gp[2*m+1] = (red[1][0]+red[1][1]) / (float)FF;
    pA[m] = make_float2(red[2][0]+red[2][1], red[3][0]+red[3][1]);
  }
}

// ---------- bn_k: blocks 0..MM-1 = statsB (local pA reduce); block MM = xg ----------
__global__ __launch_bounds__(256) void bn_k(const float* __restrict__ g, const void* __restrict__ mirna,
                                            const void* lw1, const void* lb1,
                                            const void* gw1, const void* gb1, const void* gw2,
                                            const float* __restrict__ gp,
                                            const float2* __restrict__ pA, float2* __restrict__ pB,
                                            float* __restrict__ xg2b, const int* bfp){
  __shared__ float xs[MM];
  __shared__ float red[2][4];
  __shared__ float bc[3];
  int m = blockIdx.x, tid = threadIdx.x, bf = *bfp;
  int wv = tid >> 6;
  if (m == MM){
    float g10 = ldf(gw1,0,bf), g11 = ldf(gw1,1,bf), b1v = ldf(gb1,0,bf);
    float s = 0, s2 = 0;
    for (int i = tid; i < MM; i += 256){
      float v = g10*gp[2*i] + g11*gp[2*i+1] + b1v;
      xs[i] = v; s += v; s2 += v*v;
    }
    s = waveSum(s); s2 = waveSum(s2);
    if ((tid & 63) == 0){ red[0][wv] = s; red[1][wv] = s2; }
    __syncthreads();
    if (tid == 0){
      float t  = red[0][0]+red[0][1]+red[0][2]+red[0][3];
      float t2 = red[1][0]+red[1][1]+red[1][2]+red[1][3];
      float mean = t / (float)MM, var = t2 / (float)MM - mean*mean;
      bc[0] = mean; bc[1] = rsqrtf(var + EPSV);
    }
    __syncthreads();
    float mean = bc[0], rs = bc[1];
    s = 0; s2 = 0;
    for (int i = tid; i < MM; i += 256){
      float r = (xs[i] - mean) * rs; r = r > 0.f ? r : 0.f;
      xs[i] = r; s += r; s2 += r*r;
    }
    s = waveSum(s); s2 = waveSum(s2);
    __syncthreads();
    if ((tid & 63) == 0){ red[0][wv] = s; red[1][wv] = s2; }
    __syncthreads();
    if (tid == 0){
      float t  = red[0][0]+red[0][1]+red[0][2]+red[0][3];
      float t2 = red[1][0]+red[1][1]+red[1][2]+red[1][3];
      float mrg = t / (float)MM, vrg = t2 / (float)MM - mrg*mrg;
      float g20 = ldf(gw2,0,bf), g21 = ldf(gw2,1,bf);
      bc[0] = mrg;
      bc[1] = g20 * rsqrtf(g20*g20*vrg + EPSV);
      bc[2] = g21 * rsqrtf(g21*g21*vrg + EPSV);
    }
    __syncthreads();
    float mrg = bc[0], c0 = bc[1], c1 = bc[2];
    for (int i = tid; i < MM; i += 256){
      float d = xs[i] - mrg;
      xg2b[2*i] = c0 * d; xg2b[2*i+1] = c1 * d;
    }
  } else {
    float s = 0, s2 = 0;
    for (int i = tid; i < MM; i += 256){ float2 p = pA[i]; s += p.x; s2 += p.y; }
    s = waveSum(s); s2 = waveSum(s2);
    if ((tid & 63) == 0){ red[0][wv] = s; red[1][wv] = s2; }
    __syncthreads();
    if (tid == 0){
      float t  = red[0][0]+red[0][1]+red[0][2]+red[0][3];
      float t2 = red[1][0]+red[1][1]+red[1][2]+red[1][3];
      float mu = (float)((double)t / NTOT);
      bc[0] = mu;
      bc[1] = rsqrtf((float)((double)t2 / NTOT) - mu*mu + EPSV);
    }
    __syncthreads();
    float mu1 = bc[0], rs1 = bc[1];
    int gr = m < 901 ? m : m + 282;
    float w00 = ldf(lw1,0,bf), w01 = ldf(lw1,1,bf), bb = ldf(lb1,0,bf);
    float sr = 0, sr2 = 0;
    for (int w = tid; w < FF; w += 256){
      float x0 = g[(size_t)gr * HP + w];
      float x1 = ldf(mirna, (size_t)m * FF + w, bf);
      float xl = w00*x0 + w01*x1 + bb;
      float r = (xl - mu1) * rs1; r = r > 0.f ? r : 0.f;
      sr += r; sr2 += r*r;
    }
    sr = waveSum(sr); sr2 = waveSum(sr2);
    __syncthreads();
    if ((tid & 63) == 0){ red[0][wv] = sr; red[1][wv] = sr2; }
    __syncthreads();
    if (tid == 0) pB[m] = make_float2(red[0][0]+red[0][1]+red[0][2]+red[0][3],
                                      red[1][0]+red[1][1]+red[1][2]+red[1][3]);
  }
}

// ---------- fs_k: local pA+pB reductions, then fused row -> s0/s1 dot ----------
__global__ __launch_bounds__(256) void fs_k(const float* __restrict__ g, const void* __restrict__ mirna,
                                            const void* lw1, const void* lb1, const void* lw2,
                                            const float2* __restrict__ pA, const float2* __restrict__ pB,
                                            const float* __restrict__ xg2b,
                                            const float* __restrict__ u1,
                                            float* __restrict__ s0, float* __restrict__ s1, const int* bfp){
  __shared__ float red[4][4];
  __shared__ float cst[5];   // mu1, rs1, mr, A0, A1
  int bf = *bfp;
  int m = blockIdx.x, tid = threadIdx.x;
  int wv = tid >> 6;
  {
    float a1 = 0, a2 = 0, b1 = 0, b2 = 0;
    for (int i = tid; i < MM; i += 256){
      float2 p = pA[i]; a1 += p.x; a2 += p.y;
      float2 q = pB[i]; b1 += q.x; b2 += q.y;
    }
    a1 = waveSum(a1); a2 = waveSum(a2); b1 = waveSum(b1); b2 = waveSum(b2);
    if ((tid & 63) == 0){ red[0][wv]=a1; red[1][wv]=a2; red[2][wv]=b1; red[3][wv]=b2; }
    __syncthreads();
    if (tid == 0){
      float tA  = red[0][0]+red[0][1]+red[0][2]+red[0][3];
      float tA2 = red[1][0]+red[1][1]+red[1][2]+red[1][3];
      float tB  = red[2][0]+red[2][1]+red[2][2]+red[2][3];
      float tB2 = red[3][0]+red[3][1]+red[3][2]+red[3][3];
      float mu = (float)((double)tA / NTOT);
      float rs = rsqrtf((float)((double)tA2 / NTOT) - mu*mu + EPSV);
      float mr = (float)((double)tB / NTOT);
      float vr = (float)((double)tB2 / NTOT) - mr*mr;
      float l20 = ldf(lw2,0,bf), l21 = ldf(lw2,1,bf);
      cst[0] = mu; cst[1] = rs; cst[2] = mr;
      cst[3] = l20 * rsqrtf(l20*l20*vr + EPSV);
      cst[4] = l21 * rsqrtf(l21*l21*vr + EPSV);
    }
    __syncthreads();
  }
  float mu1 = cst[0], rs1 = cst[1], mr = cst[2], A0 = cst[3], A1 = cst[4];
  int gr = m < 901 ? m : m + 282;
  float w00 = ldf(lw1,0,bf), w01 = ldf(lw1,1,bf), bb = ldf(lb1,0,bf);
  float xa = xg2b[2*m], xb = xg2b[2*m+1];
  float p0 = 0, p1 = 0;
  for (int w = tid; w < FF; w += 256){
    float x0 = g[(size_t)gr * HP + w];
    float x1 = ldf(mirna, (size_t)m * FF + w, bf);
    float xl = w00*x0 + w01*x1 + bb;
    float r = (xl - mu1) * rs1; r = r > 0.f ? r : 0.f;
    float rc = r - mr;
    float z0 = A0*rc + xa, z1 = A1*rc + xb;
    float sg0 = 1.f / (1.f + expf(-z0));
    float sg1 = 1.f / (1.f + expf(-z1));
    float f = 0.5f * (x0*sg0 + x1*sg1);
    p0 += f * u1[w]; p1 += f * u1[901 + w];
  }
  p0 = waveSum(p0); p1 = waveSum(p1);
  __syncthreads();
  if ((tid & 63) == 0){ red[0][wv] = p0; red[1][wv] = p1; }
  __syncthreads();
  if (tid == 0){
    s0[m] = red[0][0]+red[0][1]+red[0][2]+red[0][3];
    s1[m] = red[1][0]+red[1][1]+red[1][2]+red[1][3];
  }
}

// ---------- final scores ----------
__global__ __launch_bounds__(256) void out_k(const int* __restrict__ tr, const int* __restrict__ te,
                                             const float* __restrict__ s0, const float* __restrict__ s1,
                                             const float* __restrict__ cp, void* __restrict__ out,
                                             const int* bfp){
  int bf = *bfp;
  int b = blockIdx.x * 256 + threadIdx.x;
  if (b >= NOUT) return;
  int i, j;
  if (b < NTR){ i = tr[2*b]; j = tr[2*b + 1]; }
  else { int t = b - NTR; i = te[2*t]; j = te[2*t + 1]; }
  float z = s0[i] + s1[j] + cp[0] + cp[1] + cp[2];
  float v = 1.f / (1.f + expf(-z));
  if (bf) ((u16*)out)[b] = f2bf(v);
  else    ((float*)out)[b] = v;
}

extern "C" void kernel_launch(void* const* d_in, const int* in_sizes, int n_in,
                              void* d_out, int out_size, void* d_ws, size_t ws_size,
                              hipStream_t stream){
  const void* x_feat = d_in[0];
  const void* mirna  = d_in[1];
  const void* Wg     = d_in[2];
  const void* att_s  = d_in[3];
  const void* att_d  = d_in[4];
  const void* gat_b  = d_in[5];
  const void* lw1    = d_in[6];
  const void* lb1    = d_in[7];
  const void* lw2    = d_in[8];
  const void* gw1    = d_in[10];
  const void* gb1    = d_in[11];
  const void* gw2    = d_in[12];
  const void* W1     = d_in[14];
  const void* b1     = d_in[15];
  const void* W2     = d_in[16];
  const void* b2     = d_in[17];
  const void* W3     = d_in[18];
  const void* b3     = d_in[19];
  const void* W4     = d_in[20];
  const void* b4     = d_in[21];
  const int* ei      = (const int*)d_in[22];
  const int* tr      = (const int*)d_in[23];
  const int* te      = (const int*)d_in[24];

  char* ws = (char*)d_ws;
  size_t off = 0;
  auto alloc = [&](size_t bytes)->size_t{ size_t o = off; off += (bytes + 255) & ~(size_t)255; return o; };
  size_t oA  = alloc((size_t)MP*KP*2);     // padded A; later overlaid by g [NN][HP] f32
  size_t oBT = alloc((size_t)NP*KP*2);
  size_t oH  = alloc((size_t)NN*HP*2);     // h bf16, padded stride
  size_t oCS = alloc((size_t)ETOT*4);
  size_t oCW = alloc((size_t)ETOT*4);
  size_t oAS = alloc(NN*4);
  size_t oAD = alloc(NN*4);
  size_t oOF = alloc((NN+1)*4);
  size_t oGP = alloc(MM*2*4);
  size_t oXG = alloc(MM*2*4);
  size_t oS0 = alloc(MM*4);
  size_t oS1 = alloc(MM*4);
  size_t oU3 = alloc(512*4);
  size_t oU2 = alloc(1024*4);
  size_t oU1 = alloc(1802*4);
  size_t oPA = alloc(MM*8);
  size_t oPB = alloc(MM*8);
  size_t oCP = alloc(3*4);
  size_t oBF = alloc(4);
  size_t zstart = off;                     // ---- zeroed region ----
  size_t oCT = alloc(NN*4);                // counts
  size_t oFL = alloc(NN*4);                // fill
  size_t oDN = alloc(NN*4);                // denom
  size_t oWS = alloc(KP*4);                // wsv (padded k zero)
  size_t oWD = alloc(KP*4);                // wdv
  size_t zend = off;

  u16*   Ap   = (u16*)(ws+oA);
  u16*   BT   = (u16*)(ws+oBT);
  u16*   h    = (u16*)(ws+oH);
  float* gbuf = (float*)(ws+oA);           // overlay: A dead after gemm... (aggr reads only h; Ap dead)
  int*   csrS = (int*)(ws+oCS);
  float* csrW = (float*)(ws+oCW);
  float* a_s  = (float*)(ws+oAS);
  float* a_d  = (float*)(ws+oAD);
  int*   offs = (int*)(ws+oOF);
  float* gp   = (float*)(ws+oGP);
  float* xg2b = (float*)(ws+oXG);
  float* s0   = (float*)(ws+oS0);
  float* s1   = (float*)(ws+oS1);
  float* u3   = (float*)(ws+oU3);
  float* u2   = (float*)(ws+oU2);
  float* u1   = (float*)(ws+oU1);
  float2* pA  = (float2*)(ws+oPA);
  float2* pB  = (float2*)(ws+oPB);
  float* cp   = (float*)(ws+oCP);
  int*   bfp  = (int*)(ws+oBF);
  int*   cnts = (int*)(ws+oCT);
  int*   fill = (int*)(ws+oFL);
  float* denom= (float*)(ws+oDN);
  float* wsv  = (float*)(ws+oWS);
  float* wdv  = (float*)(ws+oWD);

  hipMemsetAsync(ws + zstart, 0, zend - zstart, stream);

  pad_k  <<<PAD_GRID, 256, 0, stream>>>(
      x_feat, Wg, W3, W4, b3, b4, att_s, att_d, ei, Ap, BT, u3, cp, wsv, wdv, cnts, bfp);
  scan_k <<<1029, 256, 0, stream>>>(cnts, offs, W2, b2, u3, u2, cp, Ap, wsv, wdv, a_s, a_d, bfp);
  edge2_k<<<(ETOT+255)/256, 256, 0, stream>>>(ei, a_s, a_d, denom, offs, fill, csrS, csrW);
  gemm_k <<<495 + 451, 256, 0, stream>>>(Ap, BT, h, W1, b1, u2, u1, cp, bfp);
  aggr_k <<<MM, 128, 0, stream>>>(h, offs, csrS, csrW, denom, gat_b, mirna, lw1, lb1, gbuf, gp, pA, bfp);
  bn_k   <<<MM + 1, 256, 0, stream>>>(gbuf, mirna, lw1, lb1, gw1, gb1, gw2, gp, pA, pB, xg2b, bfp);
  fs_k   <<<MM, 256, 0, stream>>>(gbuf, mirna, lw1, lb1, lw2, pA, pB, xg2b, u1, s0, s1, bfp);
  out_k  <<<(NOUT+255)/256, 256, 0, stream>>>(tr, te, s0, s1, cp, d_out, bfp);
}